// Round 8
// baseline (244.693 us; speedup 1.0000x reference)
//
#include <hip/hip_runtime.h>

typedef short short8 __attribute__((ext_vector_type(8)));
typedef float f32x4 __attribute__((ext_vector_type(4)));
typedef unsigned long long u64;

#define NE 1024
#define D 64
#define HW 4096
#define NTOK 65536
#define MARGIN 4.0e-3f
#define FLT_MAX_F 3.402823466e+38f
#define CAP 120

// ws: bn f32[1024]@0 ; ebf u16[65536]@4096 ; win u16[65536]@135168
#define WS_BN  0
#define WS_EBF 4096
#define WS_WIN 135168
// d_out overlay (16 MB): cnt u32[65536] @0 ; list u16[65536*CAP] @262144

__device__ __forceinline__ unsigned short f2bf(float f) {   // RNE f32->bf16
    unsigned u = __float_as_uint(f);
    return (unsigned short)((u + 0x7fffu + ((u >> 16) & 1u)) >> 16);
}

// numpy pairwise sum of squares, n=64 (frozen — exact since R2)
__device__ __forceinline__ float np_sum64_sq(const float* v) {
    float s[8];
#pragma unroll
    for (int j = 0; j < 8; ++j) s[j] = __fmul_rn(v[j], v[j]);
#pragma unroll
    for (int i = 8; i < 64; i += 8) {
#pragma unroll
        for (int j = 0; j < 8; ++j)
            s[j] = __fadd_rn(s[j], __fmul_rn(v[i + j], v[i + j]));
    }
    return __fadd_rn(__fadd_rn(__fadd_rn(s[0], s[1]), __fadd_rn(s[2], s[3])),
                     __fadd_rn(__fadd_rn(s[4], s[5]), __fadd_rn(s[6], s[7])));
}

__global__ __launch_bounds__(256) void kP_prep(
        const float* __restrict__ cb, float* __restrict__ bn,
        unsigned short* __restrict__ ebf, unsigned* __restrict__ cnt) {
    const int gid = blockIdx.x * 256 + threadIdx.x;   // 65536 threads
    cnt[gid] = 0u;
    ebf[gid] = f2bf(cb[gid]);
    if (gid < NE) {
        float row[D];
        const float4* r4 = reinterpret_cast<const float4*>(cb + (size_t)gid * D);
#pragma unroll
        for (int i = 0; i < 16; ++i) {
            float4 v = r4[i];
            row[4*i+0] = v.x; row[4*i+1] = v.y; row[4*i+2] = v.z; row[4*i+3] = v.w;
        }
        bn[gid] = np_sum64_sq(row);
    }
}

__global__ __launch_bounds__(256, 4) void k1_score(
        const float* __restrict__ in, const unsigned short* __restrict__ ebf,
        const float* __restrict__ bn_g, unsigned* __restrict__ cnt,
        unsigned short* __restrict__ list) {
    __shared__ unsigned short ebq[128 * 64];   // 16 KiB, XOR-swizzled (proven)
    __shared__ float sbn[128];

    // XCD-contiguous: XCD x gets token-groups [64x,64x+64), all 8 chunks
    const int sw  = (blockIdx.x & 7) * 512 + (blockIdx.x >> 3);
    const int tg  = sw >> 3;
    const int c   = sw & 7;
    const int tid  = threadIdx.x;
    const int lane = tid & 63, w = tid >> 6;
    const int lcol = lane & 15, lhi = lane >> 4, lrow = lhi * 4;
    const int tokw = tg * 128 + w * 32;

    if (tid < 128) sbn[tid] = bn_g[c * 128 + tid];
    const char* src = (const char*)(ebf + (size_t)c * 128 * 64);
#pragma unroll
    for (int i = 0; i < 4; ++i) {
        int L = (tid + i * 256) * 16;
        int row = L >> 7, wi = L & 127;
        int4 v = *(const int4*)(src + L);
        *(int4*)((char*)ebq + row * 128 + (wi ^ ((row & 7) << 4))) = v;
    }
    // rebuild B fragments from input (layout frozen since R4; L2-local via swizzle)
    const int b = tokw >> 12, hwb = tokw & 4095;
    const float* xbase = in + (size_t)b * (D * HW);
    const int hw0 = hwb + lcol, hw1 = hw0 + 16;
    const int kb = lhi * 8;
    short8 B00, B01, B10, B11;
    {
        const float* p;
        p = xbase + (size_t)kb * HW + hw0;
#pragma unroll
        for (int j = 0; j < 8; ++j) B00[j] = (short)f2bf(p[(size_t)j * HW]);
        p = xbase + (size_t)(kb + 32) * HW + hw0;
#pragma unroll
        for (int j = 0; j < 8; ++j) B01[j] = (short)f2bf(p[(size_t)j * HW]);
        p = xbase + (size_t)kb * HW + hw1;
#pragma unroll
        for (int j = 0; j < 8; ++j) B10[j] = (short)f2bf(p[(size_t)j * HW]);
        p = xbase + (size_t)(kb + 32) * HW + hw1;
#pragma unroll
        for (int j = 0; j < 8; ++j) B11[j] = (short)f2bf(p[(size_t)j * HW]);
    }
    __syncthreads();

    const int swz   = (lcol & 7) << 4;
    const int aoff0 = lcol * 128 + ((lhi * 16) ^ swz);
    const int aoff1 = lcol * 128 + ((64 + lhi * 16) ^ swz);

    // pass A: chunk-local per-token min (proven margin logic)
    float v10 = FLT_MAX_F, v11 = FLT_MAX_F;
#pragma unroll
    for (int ct = 0; ct < 8; ++ct) {
        const char* lp = (const char*)ebq + ct * 2048;
        short8 A0 = *(const short8*)(lp + aoff0);
        short8 A1 = *(const short8*)(lp + aoff1);
        f32x4 bnv = *(const f32x4*)(sbn + ct * 16 + lrow);
        f32x4 acc = {0.f, 0.f, 0.f, 0.f};
        acc = __builtin_amdgcn_mfma_f32_16x16x32_bf16(A0, B00, acc, 0, 0, 0);
        acc = __builtin_amdgcn_mfma_f32_16x16x32_bf16(A1, B01, acc, 0, 0, 0);
        f32x4 ac2 = {0.f, 0.f, 0.f, 0.f};
        ac2 = __builtin_amdgcn_mfma_f32_16x16x32_bf16(A0, B10, ac2, 0, 0, 0);
        ac2 = __builtin_amdgcn_mfma_f32_16x16x32_bf16(A1, B11, ac2, 0, 0, 0);
#pragma unroll
        for (int r = 0; r < 4; ++r) {
            v10 = fminf(v10, __fmaf_rn(-2.0f, acc[r], bnv[r]));
            v11 = fminf(v11, __fmaf_rn(-2.0f, ac2[r], bnv[r]));
        }
    }
    v10 = fminf(v10, __shfl_xor(v10, 16)); v10 = fminf(v10, __shfl_xor(v10, 32));
    v11 = fminf(v11, __shfl_xor(v11, 16)); v11 = fminf(v11, __shfl_xor(v11, 32));
    const float thr0 = v10 + MARGIN, thr1 = v11 + MARGIN;
    const int tokA = tokw + lcol, tokB = tokw + 16 + lcol;

    // pass B: recompute (bit-identical) + append candidates to per-token lists
#pragma unroll
    for (int ct = 0; ct < 8; ++ct) {
        const char* lp = (const char*)ebq + ct * 2048;
        short8 A0 = *(const short8*)(lp + aoff0);
        short8 A1 = *(const short8*)(lp + aoff1);
        f32x4 bnv = *(const f32x4*)(sbn + ct * 16 + lrow);
        f32x4 acc = {0.f, 0.f, 0.f, 0.f};
        acc = __builtin_amdgcn_mfma_f32_16x16x32_bf16(A0, B00, acc, 0, 0, 0);
        acc = __builtin_amdgcn_mfma_f32_16x16x32_bf16(A1, B01, acc, 0, 0, 0);
        f32x4 ac2 = {0.f, 0.f, 0.f, 0.f};
        ac2 = __builtin_amdgcn_mfma_f32_16x16x32_bf16(A0, B10, ac2, 0, 0, 0);
        ac2 = __builtin_amdgcn_mfma_f32_16x16x32_bf16(A1, B11, ac2, 0, 0, 0);
        const int kg = c * 128 + ct * 16 + lrow;
#pragma unroll
        for (int r = 0; r < 4; ++r) {
            float t0 = __fmaf_rn(-2.0f, acc[r], bnv[r]);
            if (t0 <= thr0) {
                unsigned pos = atomicAdd(&cnt[tokA], 1u);
                if (pos < CAP) list[(size_t)tokA * CAP + pos] = (unsigned short)(kg + r);
            }
            float t1 = __fmaf_rn(-2.0f, ac2[r], bnv[r]);
            if (t1 <= thr1) {
                unsigned pos = atomicAdd(&cnt[tokB], 1u);
                if (pos < CAP) list[(size_t)tokB * CAP + pos] = (unsigned short)(kg + r);
            }
        }
    }
}

// wave per token, lane per candidate; frozen numerics via shuffle-broadcast x
__global__ __launch_bounds__(256, 4) void k2_rerank(
        const float* __restrict__ in, const float* __restrict__ cb,
        const float* __restrict__ bn, const unsigned* __restrict__ cnt,
        const unsigned short* __restrict__ list, unsigned short* __restrict__ win) {
    // XCD-contiguous tokens: XCD x gets tokens [8192x, 8192(x+1))
    const int sw   = (blockIdx.x & 7) * 2048 + (blockIdx.x >> 3);
    const int tid  = threadIdx.x;
    const int lane = tid & 63;
    const int tok  = sw * 4 + (tid >> 6);
    const int b = tok >> 12, hw = tok & 4095;

    const float xl = in[(size_t)b * (D * HW) + (size_t)lane * HW + hw];  // lane d = x_d
    const unsigned n = cnt[tok];
    const bool fullscan = (n > CAP);          // deterministic rare fallback
    const int total = fullscan ? NE : (int)n;

    u64 best = ~0ull;
    for (int base = 0; base < total; base += 64) {
        const int i = base + lane;
        const bool active = (i < total);
        int k = 0;
        if (active) k = fullscan ? i : (int)list[(size_t)tok * CAP + i];

        const float4* e4 = reinterpret_cast<const float4*>(cb + (size_t)k * D);
        float4 e[16];
#pragma unroll
        for (int q = 0; q < 16; ++q) e[q] = e4[q];
        const float bnk = bn[k];

        float s0=0.f,s1=0.f,s2=0.f,s3=0.f,s4=0.f,s5=0.f,s6=0.f,s7=0.f;
        float dot = 0.f;
#pragma unroll
        for (int d = 0; d < 64; ++d) {
            const float xd = __shfl(xl, d);
            const float ed = (d & 3) == 0 ? e[d >> 2].x : (d & 3) == 1 ? e[d >> 2].y
                           : (d & 3) == 2 ? e[d >> 2].z : e[d >> 2].w;
            dot = __fmaf_rn(xd, ed, dot);               // frozen: sequential asc d
            const float x2 = __fmul_rn(xd, xd);         // frozen np-pairwise
            switch (d & 7) {
                case 0: s0 = __fadd_rn(s0, x2); break;
                case 1: s1 = __fadd_rn(s1, x2); break;
                case 2: s2 = __fadd_rn(s2, x2); break;
                case 3: s3 = __fadd_rn(s3, x2); break;
                case 4: s4 = __fadd_rn(s4, x2); break;
                case 5: s5 = __fadd_rn(s5, x2); break;
                case 6: s6 = __fadd_rn(s6, x2); break;
                default: s7 = __fadd_rn(s7, x2); break;
            }
        }
        const float a = __fadd_rn(__fadd_rn(__fadd_rn(s0, s1), __fadd_rn(s2, s3)),
                                  __fadd_rn(__fadd_rn(s4, s5), __fadd_rn(s6, s7)));
        const float qv = __fsub_rn(__fadd_rn(a, bnk), __fmul_rn(2.0f, dot));  // frozen
        if (active) {
            u64 key = (((u64)__float_as_uint(qv)) << 32) | (unsigned)k;  // q>0 always
            best = best < key ? best : key;
        }
    }
#pragma unroll
    for (int o = 32; o; o >>= 1) {
        u64 v = __shfl_xor(best, o);
        best = best < v ? best : v;
    }
    if (lane == 0) win[tok] = (unsigned short)(best & 0x3FFull);
}

__global__ __launch_bounds__(256) void k3_gather(
        const float* __restrict__ cb, const unsigned short* __restrict__ win,
        float* __restrict__ out) {
    const int gid = blockIdx.x * 256 + threadIdx.x;   // 262144 threads
    const int tok = gid >> 2, qd = (gid & 3) << 4;
    const int b = tok >> 12, hw = tok & 4095;
    const unsigned k = win[tok];
    const float4* er = reinterpret_cast<const float4*>(cb + (size_t)k * D + qd);
    float* ot = out + (size_t)b * (D * HW) + hw;
#pragma unroll
    for (int i = 0; i < 4; ++i) {
        float4 e = er[i];
        ot[(size_t)(qd + 4*i + 0) * HW] = e.x;
        ot[(size_t)(qd + 4*i + 1) * HW] = e.y;
        ot[(size_t)(qd + 4*i + 2) * HW] = e.z;
        ot[(size_t)(qd + 4*i + 3) * HW] = e.w;
    }
}

extern "C" void kernel_launch(void* const* d_in, const int* in_sizes, int n_in,
                              void* d_out, int out_size, void* d_ws, size_t ws_size,
                              hipStream_t stream) {
    const float* in  = (const float*)d_in[0];
    const float* cb  = (const float*)d_in[1];
    float*       out = (float*)d_out;
    char*        ws  = (char*)d_ws;

    float*          bn   = (float*)(ws + WS_BN);
    unsigned short* ebf  = (unsigned short*)(ws + WS_EBF);
    unsigned short* win  = (unsigned short*)(ws + WS_WIN);
    unsigned*       cnt  = (unsigned*)d_out;
    unsigned short* list = (unsigned short*)((char*)d_out + 262144);

    hipLaunchKernelGGL(kP_prep,   dim3(256),   dim3(256), 0, stream, cb, bn, ebf, cnt);
    hipLaunchKernelGGL(k1_score,  dim3(4096),  dim3(256), 0, stream, in, ebf, bn, cnt, list);
    hipLaunchKernelGGL(k2_rerank, dim3(16384), dim3(256), 0, stream, in, cb, bn, cnt, list, win);
    hipLaunchKernelGGL(k3_gather, dim3(1024),  dim3(256), 0, stream, cb, win, out);
}